// Round 7
// baseline (33.537 us; speedup 1.0000x reference)
//
#include <hip/hip_runtime.h>
#include <float.h>

#define BATCH 64
#define NROWS 8192
#define NCH   64
#define TOPK  9

// Insert v into descending-sorted m[0..8], keep top-9.
// r[0] = max(m[0], v); r[k] = median(m[k-1], m[k], v)  -- depth-1, 9 ops.
__device__ __forceinline__ void insert9(float (&m)[TOPK], float v) {
    const float r0 = fmaxf(m[0], v);
#pragma unroll
    for (int k = TOPK - 1; k >= 1; --k)
        m[k] = __builtin_amdgcn_fmed3f(m[k - 1], m[k], v);
    m[0] = r0;
}

// Kernel 1: per-(batch,chunk) block: top-9 per channel over its NROWS/S rows.
// S=32 -> 2048 blocks = 2 rounds at 4 blocks/CU: round-1 merge tails overlap
// round-2 streaming (tail no longer exposed at end-of-kernel).
template <int S>
__global__ __launch_bounds__(256, 4) void topk_partial(const float* __restrict__ x,
                                                       float* __restrict__ ws) {
    constexpr int RWS = NROWS / S;
    const int bx = blockIdx.x;
    const int b  = bx / S;
    const int s  = bx % S;
    const int t  = threadIdx.x;
    const int cg = t & 15;
    const int ns = t >> 4;
    const int c  = t & 63;
    const int q  = t >> 6;

    float m[4][TOPK];
#pragma unroll
    for (int ch = 0; ch < 4; ++ch)
#pragma unroll
        for (int k = 0; k < TOPK; ++k) m[ch][k] = -FLT_MAX;

    // Stream: thread owns 4 channels (float4) x RWS/16 rows; wave reads 1 KiB contig.
    const float4* xr = (const float4*)(x + ((size_t)b * NROWS + (size_t)s * RWS) * NCH);
#pragma unroll 8
    for (int k = 0; k < RWS / 16; ++k) {
        const float4 v = xr[ns * 16 + k * 256 + cg];
        insert9(m[0], v.x);
        insert9(m[1], v.y);
        insert9(m[2], v.z);
        insert9(m[3], v.w);
    }

    __shared__ float lists[16][TOPK][NCH];   // 36 KB; [ns][k][ch]
#pragma unroll
    for (int k = 0; k < TOPK; ++k) {
        float4 vv = make_float4(m[0][k], m[1][k], m[2][k], m[3][k]);
        *(float4*)&lists[ns][k][4 * cg] = vv;   // ds_write_b128, bank-optimal
    }
    __syncthreads();

    // Stage A: wave q merges ns rows 4q..4q+3 -> row 4q (lane-stride-1 reads).
    {
        float mm[TOPK];
#pragma unroll
        for (int k = 0; k < TOPK; ++k) mm[k] = lists[4 * q][k][c];
#pragma unroll
        for (int i = 1; i < 4; ++i)
#pragma unroll
            for (int k = 0; k < TOPK; ++k)
                insert9(mm, lists[4 * q + i][k][c]);
#pragma unroll
        for (int k = 0; k < TOPK; ++k) lists[4 * q][k][c] = mm[k];
    }
    __syncthreads();

    // Stage B: 64 threads merge rows 0,4,8,12; write partial to ws.
    if (t < NCH) {
        float mm[TOPK];
#pragma unroll
        for (int k = 0; k < TOPK; ++k) mm[k] = lists[0][k][t];
#pragma unroll
        for (int qq = 1; qq < 4; ++qq)
#pragma unroll
            for (int k = 0; k < TOPK; ++k)
                insert9(mm, lists[4 * qq][k][t]);
        // ws layout: [B][S][TOPK][NCH] (coalesced across channel lanes)
        float* w = ws + ((size_t)(b * S + s) * TOPK) * NCH;
#pragma unroll
        for (int k = 0; k < TOPK; ++k) w[k * NCH + t] = mm[k];
    }
}

// Kernel 2: merge S partial lists per (b,c); mean of final top-9.
template <int S>
__global__ __launch_bounds__(256, 4) void topk_final(const float* __restrict__ ws,
                                                     float* __restrict__ out) {
    constexpr int PER = S / 4;   // lists per level-1 thread
    const int b = blockIdx.x;
    const int t = threadIdx.x;
    const int c = t & 63;
    const int q = t >> 6;
    __shared__ float quarts[4][TOPK][NCH];   // 9 KB, [q][k][ch]

    const float* w = ws + (size_t)b * S * TOPK * NCH;
    float mm[TOPK];
#pragma unroll
    for (int k = 0; k < TOPK; ++k) mm[k] = w[((q * PER) * TOPK + k) * NCH + c];
#pragma unroll
    for (int i = 1; i < PER; ++i)
#pragma unroll
        for (int k = 0; k < TOPK; ++k)
            insert9(mm, w[((q * PER + i) * TOPK + k) * NCH + c]);
#pragma unroll
    for (int k = 0; k < TOPK; ++k) quarts[q][k][c] = mm[k];
    __syncthreads();

    if (t < NCH) {
        float r[TOPK];
#pragma unroll
        for (int k = 0; k < TOPK; ++k) r[k] = quarts[0][k][t];
#pragma unroll
        for (int q2 = 1; q2 < 4; ++q2)
#pragma unroll
            for (int k = 0; k < TOPK; ++k)
                insert9(r, quarts[q2][k][t]);
        float sum = 0.f;
#pragma unroll
        for (int k = 0; k < TOPK; ++k) sum += r[k];
        out[b * NCH + t] = sum * (1.0f / 9.0f);
    }
}

extern "C" void kernel_launch(void* const* d_in, const int* in_sizes, int n_in,
                              void* d_out, int out_size, void* d_ws, size_t ws_size,
                              hipStream_t stream) {
    const float* x = (const float*)d_in[0];
    float* out = (float*)d_out;
    float* ws = (float*)d_ws;

    const size_t need32 = (size_t)BATCH * 32 * TOPK * NCH * sizeof(float);  // 4.7 MB
    if (ws_size >= need32) {
        topk_partial<32><<<BATCH * 32, 256, 0, stream>>>(x, ws);
        topk_final<32><<<BATCH, 256, 0, stream>>>(ws, out);
    } else {
        topk_partial<16><<<BATCH * 16, 256, 0, stream>>>(x, ws);
        topk_final<16><<<BATCH, 256, 0, stream>>>(ws, out);
    }
}

// Round 8
// 32.124 us; speedup vs baseline: 1.0440x; 1.0440x over previous
//
#include <hip/hip_runtime.h>
#include <float.h>

#define BATCH 64
#define NROWS 8192
#define NCH   64
#define SCHNK 16                 // N-chunks per batch
#define ROWS  (NROWS / SCHNK)    // 512 rows per block
#define TOPK  9

typedef float f32x4 __attribute__((ext_vector_type(4)));

// Insert v into descending-sorted m[0..8], keep top-9.
// r[0] = max(m[0], v); r[k] = median(m[k-1], m[k], v)  -- depth-1, 9 ops.
__device__ __forceinline__ void insert9(float (&m)[TOPK], float v) {
    const float r0 = fmaxf(m[0], v);
#pragma unroll
    for (int k = TOPK - 1; k >= 1; --k)
        m[k] = __builtin_amdgcn_fmed3f(m[k - 1], m[k], v);
    m[0] = r0;
}

// Kernel 1: per-(batch,chunk) block: top-9 per channel over its 512 rows.
// Stream loads are non-temporal (read-once data: skip L2/L3 allocation).
// 36 KB LDS -> 4 blocks/CU, all 1024 blocks co-resident.
__global__ __launch_bounds__(256, 4) void topk_partial(const float* __restrict__ x,
                                                       float* __restrict__ ws) {
    const int bx = blockIdx.x;
    const int b  = bx >> 4;
    const int s  = bx & (SCHNK - 1);
    const int t  = threadIdx.x;
    const int cg = t & 15;
    const int ns = t >> 4;
    const int c  = t & 63;
    const int q  = t >> 6;

    float m[4][TOPK];
#pragma unroll
    for (int ch = 0; ch < 4; ++ch)
#pragma unroll
        for (int k = 0; k < TOPK; ++k) m[ch][k] = -FLT_MAX;

    // Stream: thread owns 4 channels (f32x4) x 32 rows; wave reads 1 KiB contig;
    // block walks 4 KiB/iter sequential.
    const f32x4* xr = (const f32x4*)(x + ((size_t)b * NROWS + (size_t)s * ROWS) * NCH);
#pragma unroll 16
    for (int k = 0; k < ROWS / 16; ++k) {
        const f32x4 v = __builtin_nontemporal_load(xr + ns * 16 + k * 256 + cg);
        insert9(m[0], v[0]);
        insert9(m[1], v[1]);
        insert9(m[2], v[2]);
        insert9(m[3], v[3]);
    }

    __shared__ float lists[16][TOPK][NCH];   // 36 KB; [ns][k][ch]
#pragma unroll
    for (int k = 0; k < TOPK; ++k) {
        float4 vv = make_float4(m[0][k], m[1][k], m[2][k], m[3][k]);
        *(float4*)&lists[ns][k][4 * cg] = vv;   // ds_write_b128, bank-optimal
    }
    __syncthreads();

    // Stage A: wave q merges ns rows 4q..4q+3 -> row 4q (lane-stride-1 reads).
    {
        float mm[TOPK];
#pragma unroll
        for (int k = 0; k < TOPK; ++k) mm[k] = lists[4 * q][k][c];
#pragma unroll
        for (int i = 1; i < 4; ++i)
#pragma unroll
            for (int k = 0; k < TOPK; ++k)
                insert9(mm, lists[4 * q + i][k][c]);
#pragma unroll
        for (int k = 0; k < TOPK; ++k) lists[4 * q][k][c] = mm[k];
    }
    __syncthreads();

    // Stage B: 64 threads merge rows 0,4,8,12; write partial to ws.
    if (t < NCH) {
        float mm[TOPK];
#pragma unroll
        for (int k = 0; k < TOPK; ++k) mm[k] = lists[0][k][t];
#pragma unroll
        for (int qq = 1; qq < 4; ++qq)
#pragma unroll
            for (int k = 0; k < TOPK; ++k)
                insert9(mm, lists[4 * qq][k][t]);
        // ws layout: [B][SCHNK][TOPK][NCH] (coalesced across channel lanes)
        float* w = ws + ((size_t)(b * SCHNK + s) * TOPK) * NCH;
#pragma unroll
        for (int k = 0; k < TOPK; ++k) w[k * NCH + t] = mm[k];
    }
}

// Kernel 2: merge SCHNK partial lists per (b,c); mean of final top-9.
__global__ __launch_bounds__(256, 4) void topk_final(const float* __restrict__ ws,
                                                     float* __restrict__ out) {
    const int b = blockIdx.x;
    const int t = threadIdx.x;
    const int c = t & 63;
    const int q = t >> 6;
    __shared__ float quarts[4][TOPK][NCH];   // 9 KB, [q][k][ch]

    const float* w = ws + (size_t)b * SCHNK * TOPK * NCH;
    float mm[TOPK];
#pragma unroll
    for (int k = 0; k < TOPK; ++k) mm[k] = w[((q * 4) * TOPK + k) * NCH + c];
#pragma unroll
    for (int i = 1; i < 4; ++i)
#pragma unroll
        for (int k = 0; k < TOPK; ++k)
            insert9(mm, w[((q * 4 + i) * TOPK + k) * NCH + c]);
#pragma unroll
    for (int k = 0; k < TOPK; ++k) quarts[q][k][c] = mm[k];
    __syncthreads();

    if (t < NCH) {
        float r[TOPK];
#pragma unroll
        for (int k = 0; k < TOPK; ++k) r[k] = quarts[0][k][t];
#pragma unroll
        for (int q2 = 1; q2 < 4; ++q2)
#pragma unroll
            for (int k = 0; k < TOPK; ++k)
                insert9(r, quarts[q2][k][t]);
        float sum = 0.f;
#pragma unroll
        for (int k = 0; k < TOPK; ++k) sum += r[k];
        out[b * NCH + t] = sum * (1.0f / 9.0f);
    }
}

extern "C" void kernel_launch(void* const* d_in, const int* in_sizes, int n_in,
                              void* d_out, int out_size, void* d_ws, size_t ws_size,
                              hipStream_t stream) {
    const float* x = (const float*)d_in[0];
    float* out = (float*)d_out;
    float* ws = (float*)d_ws;   // needs B*S*9*C*4 = 2.25 MiB

    topk_partial<<<BATCH * SCHNK, 256, 0, stream>>>(x, ws);
    topk_final<<<BATCH, 256, 0, stream>>>(ws, out);
}

// Round 9
// 30.620 us; speedup vs baseline: 1.0952x; 1.0491x over previous
//
#include <hip/hip_runtime.h>
#include <float.h>

#define BATCH 64
#define NROWS 8192
#define NCH   64
#define SCHNK 16                 // N-chunks per batch
#define ROWS  (NROWS / SCHNK)    // 512 rows per block
#define TOPK  9

// Insert v into descending-sorted m[0..8], keep top-9.
// r[0] = max(m[0], v); r[k] = median(m[k-1], m[k], v)  -- depth-1, 9 ops.
__device__ __forceinline__ void insert9(float (&m)[TOPK], float v) {
    const float r0 = fmaxf(m[0], v);
#pragma unroll
    for (int k = TOPK - 1; k >= 1; --k)
        m[k] = __builtin_amdgcn_fmed3f(m[k - 1], m[k], v);
    m[0] = r0;
}

// Kernel 1: per-(batch,chunk) block: top-9 per channel over its 512 rows.
// Default-cached loads (x is ~50% L3-resident across replays -- nt loads
// measurably regress by breaking that). 36 KB LDS -> 4 blocks/CU.
__global__ __launch_bounds__(256, 4) void topk_partial(const float* __restrict__ x,
                                                       float* __restrict__ ws) {
    const int bx = blockIdx.x;
    const int b  = bx >> 4;
    const int s  = bx & (SCHNK - 1);
    const int t  = threadIdx.x;
    const int cg = t & 15;
    const int ns = t >> 4;
    const int c  = t & 63;
    const int q  = t >> 6;

    float m[4][TOPK];
#pragma unroll
    for (int ch = 0; ch < 4; ++ch)
#pragma unroll
        for (int k = 0; k < TOPK; ++k) m[ch][k] = -FLT_MAX;

    // Stream: thread owns 4 channels (float4) x 32 rows; wave reads 1 KiB contig.
    const float4* xr = (const float4*)(x + ((size_t)b * NROWS + (size_t)s * ROWS) * NCH);
#pragma unroll 8
    for (int k = 0; k < ROWS / 16; ++k) {
        const float4 v = xr[ns * 16 + k * 256 + cg];
        insert9(m[0], v.x);
        insert9(m[1], v.y);
        insert9(m[2], v.z);
        insert9(m[3], v.w);
    }

    __shared__ float lists[16][TOPK][NCH];   // 36 KB; [ns][k][ch]
#pragma unroll
    for (int k = 0; k < TOPK; ++k) {
        float4 vv = make_float4(m[0][k], m[1][k], m[2][k], m[3][k]);
        *(float4*)&lists[ns][k][4 * cg] = vv;   // ds_write_b128, bank-optimal
    }
    __syncthreads();

    // Stage A: wave q merges ns rows 4q..4q+3 -> row 4q (lane-stride-1 reads).
    {
        float mm[TOPK];
#pragma unroll
        for (int k = 0; k < TOPK; ++k) mm[k] = lists[4 * q][k][c];
#pragma unroll
        for (int i = 1; i < 4; ++i)
#pragma unroll
            for (int k = 0; k < TOPK; ++k)
                insert9(mm, lists[4 * q + i][k][c]);
#pragma unroll
        for (int k = 0; k < TOPK; ++k) lists[4 * q][k][c] = mm[k];
    }
    __syncthreads();

    // Stage B: 64 threads merge rows 0,4,8,12; write partial to ws.
    if (t < NCH) {
        float mm[TOPK];
#pragma unroll
        for (int k = 0; k < TOPK; ++k) mm[k] = lists[0][k][t];
#pragma unroll
        for (int qq = 1; qq < 4; ++qq)
#pragma unroll
            for (int k = 0; k < TOPK; ++k)
                insert9(mm, lists[4 * qq][k][t]);
        // ws layout: [B][SCHNK][TOPK][NCH] (coalesced across channel lanes)
        float* w = ws + ((size_t)(b * SCHNK + s) * TOPK) * NCH;
#pragma unroll
        for (int k = 0; k < TOPK; ++k) w[k * NCH + t] = mm[k];
    }
}

// Kernel 2: merge SCHNK partial lists per (b,c); mean of final top-9.
__global__ __launch_bounds__(256, 4) void topk_final(const float* __restrict__ ws,
                                                     float* __restrict__ out) {
    const int b = blockIdx.x;
    const int t = threadIdx.x;
    const int c = t & 63;
    const int q = t >> 6;
    __shared__ float quarts[4][TOPK][NCH];   // 9 KB, [q][k][ch]

    const float* w = ws + (size_t)b * SCHNK * TOPK * NCH;
    float mm[TOPK];
#pragma unroll
    for (int k = 0; k < TOPK; ++k) mm[k] = w[((q * 4) * TOPK + k) * NCH + c];
#pragma unroll
    for (int i = 1; i < 4; ++i)
#pragma unroll
        for (int k = 0; k < TOPK; ++k)
            insert9(mm, w[((q * 4 + i) * TOPK + k) * NCH + c]);
#pragma unroll
    for (int k = 0; k < TOPK; ++k) quarts[q][k][c] = mm[k];
    __syncthreads();

    if (t < NCH) {
        float r[TOPK];
#pragma unroll
        for (int k = 0; k < TOPK; ++k) r[k] = quarts[0][k][t];
#pragma unroll
        for (int q2 = 1; q2 < 4; ++q2)
#pragma unroll
            for (int k = 0; k < TOPK; ++k)
                insert9(r, quarts[q2][k][t]);
        float sum = 0.f;
#pragma unroll
        for (int k = 0; k < TOPK; ++k) sum += r[k];
        out[b * NCH + t] = sum * (1.0f / 9.0f);
    }
}

extern "C" void kernel_launch(void* const* d_in, const int* in_sizes, int n_in,
                              void* d_out, int out_size, void* d_ws, size_t ws_size,
                              hipStream_t stream) {
    const float* x = (const float*)d_in[0];
    float* out = (float*)d_out;
    float* ws = (float*)d_ws;   // needs B*S*9*C*4 = 2.25 MiB

    topk_partial<<<BATCH * SCHNK, 256, 0, stream>>>(x, ws);
    topk_final<<<BATCH, 256, 0, stream>>>(ws, out);
}